// Round 5
// baseline (135.316 us; speedup 1.0000x reference)
//
#include <hip/hip_runtime.h>
#include <hip/hip_bf16.h>
#include <stdint.h>

// Problem constants (fixed by reference)
#define B_  4
#define N_  8192
#define M_  8192
#define D_  64
#define NT_ 64    // N_/128
#define RBN ((B_ * N_) / 16)   // 2048 16-row blocks on A side
#define INF_BITS 0x7F800000    // +inf float bits; all stored mins are full squared dists (>=0),
                               // so signed-int atomicMin == float min

typedef __attribute__((ext_vector_type(8))) short bhalf8;   // 8 bf16 (MFMA A/B frag)
typedef __attribute__((ext_vector_type(4))) float f32x4;    // MFMA C/D frag

// ---- workspace layout (bytes) ----
// A'/B': bf16, K=64 (2 k-steps of 32). Fragment-chunk order:
//   chunk(rb, ks=0..1, lane=q*16+c) = row (rb*16+c), k = ks*32 + q*8 .. +7,
//   at ((rb*2+ks)*64 + lane)*8 elems -> lane-contiguous 1KB loads.
// nA/nB: exact fp32 ||row||^2 per point (row norms ride the MFMA C-operand;
//   col norms added in the process epilogue from an LDS broadcast table).
// rowglob/colglob: per-point global mins as float BIT PATTERNS (int), atomicMin-accumulated.
static const size_t OFF_A  = 0;
static const size_t OFF_B  = (size_t)B_ * N_ * D_ * 2;                 // 4,194,304
static const size_t OFF_NA = OFF_B + (size_t)B_ * M_ * D_ * 2;         // 8,388,608
static const size_t OFF_NB = OFF_NA + (size_t)B_ * N_ * 4;             // +128 KB
static const size_t OFF_RG = OFF_NB + (size_t)B_ * M_ * 4;             // +128 KB
static const size_t OFF_CG = OFF_RG + (size_t)B_ * N_ * 4;             // +128 KB
// end: OFF_CG + 128 KB = 8,912,896

__device__ __forceinline__ short bf16bits(float x) {
    union { __hip_bfloat16 h; unsigned short u; } cv;
    cv.h = __float2bfloat16(x);
    return (short)cv.u;
}
__device__ __forceinline__ float min3f(float a, float b, float c) {
    return fminf(fminf(a, b), c);   // -> v_min3_f32
}
__device__ __forceinline__ void gload_lds16(const unsigned short* g, unsigned short* l) {
    // async 16B/lane global->LDS; LDS dest = wave-uniform base + lane*16 (linear copy)
    __builtin_amdgcn_global_load_lds(
        (const __attribute__((address_space(1))) void*)g,
        (__attribute__((address_space(3))) void*)l, 16, 0, 0);
}

#define WAIT_VMCNT5 asm volatile("s_waitcnt vmcnt(5)" ::: "memory")
#define WAIT_VMCNT0 asm volatile("s_waitcnt vmcnt(0)" ::: "memory")
#define LGKM0       asm volatile("s_waitcnt lgkmcnt(0)" ::: "memory")
#define BARRIER     __builtin_amdgcn_s_barrier()

// ---------------- prep: K=64 fragment layout + fp32 norms; init global min buffers + out ----------------
__global__ __launch_bounds__(256) void chamfer_prep(
        const float* __restrict__ f, const float* __restrict__ f2,
        unsigned short* __restrict__ Ap, unsigned short* __restrict__ Bp,
        float* __restrict__ nA, float* __restrict__ nB,
        int* __restrict__ minbuf, float* __restrict__ out) {
    const int tid = threadIdx.x;
    const int gid = blockIdx.x * 256 + tid;
    if (gid == 0) out[0] = 0.f;                      // finalize atomicAdds into this
    if (gid < 65536) minbuf[gid] = INF_BITS;         // rowglob(32K ints) + colglob(32K ints)

    const int w = gid >> 6;                          // 16-row block id, 0..4095
    const int lane = tid & 63;
    const int q = lane >> 4, c = lane & 15;
    const bool isA = w < RBN;
    const int rb = isA ? w : w - RBN;
    const float* src = isA ? f : f2;
    unsigned short* dst = isA ? Ap : Bp;
    float* ndst = isA ? nA : nB;
    const float scale = isA ? -2.0f : 1.0f;          // fold the -2 into A; exact in bf16

    const float* row = src + ((size_t)rb * 16 + c) * 64;
    f32x4 u0 = *(const f32x4*)(row + q * 8);
    f32x4 u1 = *(const f32x4*)(row + q * 8 + 4);
    f32x4 u2 = *(const f32x4*)(row + 32 + q * 8);
    f32x4 u3 = *(const f32x4*)(row + 32 + q * 8 + 4);

    float ss = 0.f;
    #pragma unroll
    for (int k = 0; k < 4; k++)
        ss += u0[k] * u0[k] + u1[k] * u1[k] + u2[k] * u2[k] + u3[k] * u3[k];
    ss += __shfl_xor(ss, 16, 64);
    ss += __shfl_xor(ss, 32, 64);                    // full ||row c||^2 in every lane (fp32, exact)

    bhalf8 o0, o1;
    #pragma unroll
    for (int k = 0; k < 4; k++) {
        o0[k]     = bf16bits(u0[k] * scale);
        o0[4 + k] = bf16bits(u1[k] * scale);
        o1[k]     = bf16bits(u2[k] * scale);
        o1[4 + k] = bf16bits(u3[k] * scale);
    }
    if (q == 0) ndst[rb * 16 + c] = ss;              // 16 consecutive floats per wave
    *(bhalf8*)(dst + ((size_t)(rb * 2 + 0) * 64 + lane) * 8) = o0;
    *(bhalf8*)(dst + ((size_t)(rb * 2 + 1) * 64 + lane) * 8) = o1;
}

// ---------------- tile kernel: global_load_lds ring + counted vmcnt pipeline ----------------
// grid (mcp=4, nt=64, b=4) = 1024 blocks; wave tile 64 rows x 32 cols/step, 32 steps.
// B staged 3 steps ahead into a 4-slot x 8KB LDS ring via global_load_lds (zero VGPR cost,
// depth pinned by counted vmcnt -> compiler cannot collapse it). One lgkm-drain + raw
// s_barrier per step; NEVER __syncthreads in-loop (it would drain vmcnt(0)).
// vmcnt(5) derivation: per phase each wave issues 2 staging loads; 2 phases in flight = 4,
// plus exactly one flush atomic interleaved in any 2 consecutive phases = 5 newer VMEM ops
// than the loads being waited for. Neutral atomicMin(+inf) ops keep the queue shape
// invariant in the prologue and at g==0 (vmcnt retires strictly in issue order, m135).
__global__ __launch_bounds__(256) void chamfer_tile(
        const unsigned short* __restrict__ Ap, const unsigned short* __restrict__ Bp,
        const float* __restrict__ nA, const float* __restrict__ nB,
        int* __restrict__ rowglob, int* __restrict__ colglob) {
    const int mcp = blockIdx.x;  // 0..3 : 2048-col chunk-pair
    const int nt = blockIdx.y;   // 0..63
    const int b  = blockIdx.z;   // 0..3
    const int tid = threadIdx.x;
    const int wave = tid >> 6, lane = tid & 63;
    const int wr = wave >> 1, wc = wave & 1;
    const int q = lane >> 4, c = lane & 15;

    __shared__ unsigned short ring[16384];  // 32 KB: 4 slots x 8KB (2 pieces x 4KB per step)
    __shared__ float colstore[2048];        // 8 KB: 4 step-slots x 4 waves x 128 (write-once)
    __shared__ float nyb2[2048];            // 8 KB: BOTH chunks' col norms (prologue-written)
    __shared__ int rowmin[128];

    const int B0 = b * 512 + mcp * 128;

    // ---- prologue: nyb (both chunks), rowmin init, A fragments + row norms ----
    *(f32x4*)&nyb2[tid * 4] = *(const f32x4*)(nB + (size_t)b * 8192 + mcp * 2048 + tid * 4);
    *(f32x4*)&nyb2[1024 + tid * 4] =
        *(const f32x4*)(nB + (size_t)b * 8192 + mcp * 2048 + 1024 + tid * 4);
    if (tid < 128) rowmin[tid] = INF_BITS;

    const int rbA0 = b * 512 + nt * 8 + wr * 4;
    bhalf8 af[4][2];
    #pragma unroll
    for (int i = 0; i < 4; i++)
        #pragma unroll
        for (int ks = 0; ks < 2; ks++)
            af[i][ks] = *(const bhalf8*)(Ap + ((size_t)((rbA0 + i) * 2 + ks) * 64 + lane) * 8);

    f32x4 cnx[4];
    {
        const float* nrow = nA + (size_t)b * 8192 + nt * 128 + wr * 64 + q * 4;
        #pragma unroll
        for (int i = 0; i < 4; i++)
            cnx[i] = *(const f32x4*)(nrow + i * 16);
    }

    f32x4 rv[4];
    #pragma unroll
    for (int i = 0; i < 4; i++) rv[i] = (f32x4){3.0e38f, 3.0e38f, 3.0e38f, 3.0e38f};

    // stage step sIssue into ring slot sIssue&3: wave w copies sub-block t=w*2+j (1KB each);
    // piece p = t>>2 (wc half), quarter = t&3. Linear copy, fragment layout preserved.
    auto stage = [&](int sIssue) {
        const int slot = sIssue & 3;
        const int sSrc = sIssue < 32 ? sIssue : 31;   // tail clamp (duplicate, never consumed)
        #pragma unroll
        for (int j = 0; j < 2; j++) {
            const int t = wave * 2 + j;
            const int rbp = B0 + ((sSrc >> 1) << 3) + ((sSrc & 1) << 1) + ((t >> 2) << 2);
            const unsigned short* gsrc = Bp + (size_t)rbp * 1024 + (t & 3) * 512 + lane * 8;
            gload_lds16(gsrc, &ring[slot * 4096 + t * 512]);
        }
    };

    auto consume = [&](int s) {
        const int slot = s & 3;
        bhalf8 bf[2][2];
        #pragma unroll
        for (int jj = 0; jj < 2; jj++)
            #pragma unroll
            for (int ks = 0; ks < 2; ks++)
                bf[jj][ks] = *(const bhalf8*)&ring[slot * 4096 + wc * 2048 + jj * 1024 +
                                                   ks * 512 + lane * 8];

        const int cb = (s >> 1) * 128 + wc * 64 + (s & 1) * 32 + c;
        const float ny0 = nyb2[cb];       // 4-way same-address broadcast, free
        const float ny1 = nyb2[cb + 16];

        f32x4 acc[4][2];
        #pragma unroll
        for (int i = 0; i < 4; i++)
            #pragma unroll
            for (int jj = 0; jj < 2; jj++)
                acc[i][jj] = __builtin_amdgcn_mfma_f32_16x16x32_bf16(af[i][0], bf[jj][0], cnx[i], 0, 0, 0);
        #pragma unroll
        for (int i = 0; i < 4; i++)
            #pragma unroll
            for (int jj = 0; jj < 2; jj++)
                acc[i][jj] = __builtin_amdgcn_mfma_f32_16x16x32_bf16(af[i][1], bf[jj][1], acc[i][jj], 0, 0, 0);

        float sv[4][2][4];
        #pragma unroll
        for (int i = 0; i < 4; i++)
            #pragma unroll
            for (int r = 0; r < 4; r++) {
                sv[i][0][r] = acc[i][0][r] + ny0;
                sv[i][1][r] = acc[i][1][r] + ny1;
                rv[i][r] = min3f(sv[i][0][r], sv[i][1][r], rv[i][r]);
            }

        float t[2];
        #pragma unroll
        for (int jj = 0; jj < 2; jj++) {
            float t0 = min3f(sv[0][jj][0], sv[0][jj][1], sv[0][jj][2]);
            float t1 = min3f(sv[0][jj][3], sv[1][jj][0], sv[1][jj][1]);
            float t2 = min3f(sv[1][jj][2], sv[1][jj][3], sv[2][jj][0]);
            float t3 = min3f(sv[2][jj][1], sv[2][jj][2], sv[2][jj][3]);
            float t4 = min3f(sv[3][jj][0], sv[3][jj][1], sv[3][jj][2]);
            t[jj] = fminf(min3f(t0, t1, t2), min3f(t3, t4, sv[3][jj][3]));
        }
        *(float2*)&colstore[((slot * 4 + wave) * 64 + lane) * 2] = make_float2(t[0], t[1]);
    };

    // flush fg (steps 2fg, 2fg+1 -> cols [fg*128, fg*128+128)): reduce 8 contributors/col,
    // ONE full-wave atomicMin instruction (tid>=128 lanes write +inf = no-op) so the vmcnt
    // queue gains exactly 1 op for EVERY wave. neutral=true makes the whole op a no-op.
    auto flushg = [&](int fg, bool neutral) {
        const int fgq = neutral ? 0 : fg;
        const int fc = tid & 127;
        const int wcx = (fc >> 6) & 1, hf = (fc >> 5) & 1;
        const int jf = (fc >> 4) & 1, cx = fc & 15;
        const int slot4 = ((fgq & 1) << 1) | hf;       // (2*fg+hf)&3
        float m = __int_as_float(INF_BITS);
        #pragma unroll
        for (int wrx = 0; wrx < 2; wrx++) {
            const int fb = (slot4 * 4 + wrx * 2 + wcx) * 128 + cx * 2 + jf;
            float m0 = fminf(colstore[fb],      colstore[fb + 32]);
            float m1 = fminf(colstore[fb + 64], colstore[fb + 96]);
            m = fminf(m, fminf(m0, m1));
        }
        const int v = (!neutral && tid < 128) ? __float_as_int(m) : INF_BITS;
        atomicMin(&colglob[(size_t)b * 8192 + mcp * 2048 + fgq * 128 + fc], v);
    };

    // ---- pipeline prologue: drain setup loads, stage steps 0..2, shape-op last ----
    WAIT_VMCNT0;
    stage(0);
    stage(1);
    stage(2);
    __builtin_amdgcn_sched_barrier(0);    // pin the shape-op AFTER the 6 staging loads
    atomicMin(&colglob[(size_t)b * 8192 + mcp * 2048 + tid], INF_BITS);  // neutral shape op
    __builtin_amdgcn_sched_barrier(0);

    // ---- main loop: 8 groups x 4 phases; flush every 2 steps (disjoint colstore slots) ----
    #pragma unroll 1
    for (int g = 0; g < 8; g++) {
        const int s0 = g * 4;
        WAIT_VMCNT5; LGKM0; BARRIER;
        flushg(2 * g - 1, g == 0);        // reads slots {2,3}; consume(s0) writes slot 0
        stage(s0 + 3); consume(s0);
        WAIT_VMCNT5; LGKM0; BARRIER;
        stage(s0 + 4); consume(s0 + 1);
        WAIT_VMCNT5; LGKM0; BARRIER;
        flushg(2 * g, false);             // reads slots {0,1}; consume(s0+2) writes slot 2
        stage(s0 + 5); consume(s0 + 2);
        WAIT_VMCNT5; LGKM0; BARRIER;
        stage(s0 + 6); consume(s0 + 3);
    }

    // ---- epilogue: row-min flush, final col flush ----
    #pragma unroll
    for (int i = 0; i < 4; i++)
        #pragma unroll
        for (int r = 0; r < 4; r++)
            atomicMin(&rowmin[wr * 64 + i * 16 + q * 4 + r], __float_as_int(rv[i][r]));
    LGKM0; BARRIER;
    flushg(15, false);                    // steps 30,31 (slots {2,3})
    if (tid < 128)
        atomicMin(&rowglob[(size_t)(b * 64 + nt) * 128 + tid], rowmin[tid]);
}

// ---------------- finalize: mean of rowglob + colglob (256 KB total) ----------------
__global__ __launch_bounds__(256) void chamfer_finalize(
        const int* __restrict__ rowglob, const int* __restrict__ colglob,
        float* __restrict__ out) {
    const int gid = blockIdx.x * 256 + threadIdx.x;   // 64 blocks -> 16384 threads
    float s = 0.f;
    #pragma unroll
    for (int k = 0; k < 2; k++) {
        s += __int_as_float(rowglob[gid + k * 16384]) * (1.0f / ((float)B_ * (float)N_));
        s += __int_as_float(colglob[gid + k * 16384]) * (1.0f / ((float)B_ * (float)M_));
    }
    __shared__ float sb[256];
    const int tid = threadIdx.x;
    sb[tid] = s;
    __syncthreads();
    for (int st = 128; st > 0; st >>= 1) {
        if (tid < st) sb[tid] += sb[tid + st];
        __syncthreads();
    }
    if (tid == 0) atomicAdd(out, sb[0]);
}

extern "C" void kernel_launch(void* const* d_in, const int* in_sizes, int n_in,
                              void* d_out, int out_size, void* d_ws, size_t ws_size,
                              hipStream_t stream) {
    const float* f  = (const float*)d_in[0];
    const float* f2 = (const float*)d_in[1];
    char* ws = (char*)d_ws;
    unsigned short* Ap = (unsigned short*)(ws + OFF_A);
    unsigned short* Bp = (unsigned short*)(ws + OFF_B);
    float* nA    = (float*)(ws + OFF_NA);
    float* nB    = (float*)(ws + OFF_NB);
    int* rowglob = (int*)(ws + OFF_RG);
    int* colglob = (int*)(ws + OFF_CG);
    float* out   = (float*)d_out;

    // prep: K=64 fragment layout + fp32 norms; inits rowglob/colglob/out
    chamfer_prep<<<dim3(1024), dim3(256), 0, stream>>>(f, f2, Ap, Bp, nA, nB, rowglob, out);

    // main: 1024 blocks, 32-step loop, global_load_lds ring + counted-vmcnt pipeline
    chamfer_tile<<<dim3(4, NT_, B_), dim3(256), 0, stream>>>(Ap, Bp, nA, nB, rowglob, colglob);

    // finalize: 256 KB read + block sums -> scalar
    chamfer_finalize<<<dim3(64), dim3(256), 0, stream>>>(rowglob, colglob, out);
}

// Round 7
// 133.895 us; speedup vs baseline: 1.0106x; 1.0106x over previous
//
#include <hip/hip_runtime.h>
#include <hip/hip_bf16.h>
#include <stdint.h>

// Problem constants (fixed by reference)
#define B_  4
#define N_  8192
#define M_  8192
#define D_  64
#define NT_ 64    // N_/128
#define RBN ((B_ * N_) / 16)   // 2048 16-row blocks on A side
#define INF_BITS 0x7F800000    // +inf float bits; stored mins are squared dists (>=0 for this
                               // data), so signed-int atomicMin == float min (as all passing rounds)

typedef __attribute__((ext_vector_type(8))) short bhalf8;   // 8 bf16 (MFMA A/B frag)
typedef __attribute__((ext_vector_type(4))) float f32x4;    // MFMA C/D frag

// ---- workspace layout (bytes) ----  TOTAL 11,272,192 (~10.75 MB) — under the 12.84 MB
// envelope proven by rounds 0-5 (round-6's 17.6 MB layout is the prime suspect for the
// container kill; this round keeps the same experiment inside the proven footprint).
// A'/B': bf16, K=64 (2 k-steps of 32), fragment-chunk order as all rounds.
// nA/nB: exact fp32 ||row||^2 (row norms ride the MFMA C-operand; col norms added in epilogue).
// rowpart: plain disjoint per-mcp row partials (no atomics). colpart: 16 slots (nt&15) of
// col partials, fire-and-forget atomicMin at only 4-way contention (vs 64-70-way in round 4).
// NOTE: tile's 2-ahead pipeline over-reads Bp by up to 2 steps at the end (b=3, mcp=3):
// max byte = OFF_B + ~4,210,704 = 8,405,008 -> lands in the nA region, inside workspace.
static const size_t OFF_A  = 0;                                        // 4,194,304
static const size_t OFF_B  = (size_t)B_ * N_ * D_ * 2;                 // 4,194,304
static const size_t OFF_NA = OFF_B + (size_t)B_ * M_ * D_ * 2;         // 8,388,608
static const size_t OFF_NB = OFF_NA + (size_t)B_ * N_ * 4;             // 8,519,680
static const size_t OFF_RP = OFF_NB + (size_t)B_ * M_ * 4;             // 8,650,752  rowpart: 4 x 32768 f
static const size_t OFF_CP = OFF_RP + (size_t)4 * B_ * N_ * 4;         // 9,175,040  colpart: B_ x 16 x 8192 int
// end: OFF_CP + 2,097,152 = 11,272,192

__device__ __forceinline__ short bf16bits(float x) {
    union { __hip_bfloat16 h; unsigned short u; } cv;
    cv.h = __float2bfloat16(x);
    return (short)cv.u;
}
__device__ __forceinline__ float min3f(float a, float b, float c) {
    return fminf(fminf(a, b), c);   // -> v_min3_f32
}

// ---------------- prep: K=64 fragment layout + fp32 norms; init colpart + out ----------------
__global__ __launch_bounds__(256) void chamfer_prep(
        const float* __restrict__ f, const float* __restrict__ f2,
        unsigned short* __restrict__ Ap, unsigned short* __restrict__ Bp,
        float* __restrict__ nA, float* __restrict__ nB,
        int* __restrict__ colpart, float* __restrict__ out) {
    const int tid = threadIdx.x;
    const int gid = blockIdx.x * 256 + tid;          // 1024 blocks -> 262,144 threads
    if (gid == 0) out[0] = 0.f;                      // finalize atomicAdds into this
    colpart[gid] = INF_BITS;                         // 524,288 ints: 2 per thread
    colpart[gid + 262144] = INF_BITS;

    const int w = gid >> 6;                          // 16-row block id, 0..4095
    const int lane = tid & 63;
    const int q = lane >> 4, c = lane & 15;
    const bool isA = w < RBN;
    const int rb = isA ? w : w - RBN;
    const float* src = isA ? f : f2;
    unsigned short* dst = isA ? Ap : Bp;
    float* ndst = isA ? nA : nB;
    const float scale = isA ? -2.0f : 1.0f;          // fold the -2 into A; exact in bf16

    const float* row = src + ((size_t)rb * 16 + c) * 64;
    f32x4 u0 = *(const f32x4*)(row + q * 8);
    f32x4 u1 = *(const f32x4*)(row + q * 8 + 4);
    f32x4 u2 = *(const f32x4*)(row + 32 + q * 8);
    f32x4 u3 = *(const f32x4*)(row + 32 + q * 8 + 4);

    float ss = 0.f;
    #pragma unroll
    for (int k = 0; k < 4; k++)
        ss += u0[k] * u0[k] + u1[k] * u1[k] + u2[k] * u2[k] + u3[k] * u3[k];
    ss += __shfl_xor(ss, 16, 64);
    ss += __shfl_xor(ss, 32, 64);                    // full ||row c||^2 in every lane (fp32, exact)

    bhalf8 o0, o1;
    #pragma unroll
    for (int k = 0; k < 4; k++) {
        o0[k]     = bf16bits(u0[k] * scale);
        o0[4 + k] = bf16bits(u1[k] * scale);
        o1[k]     = bf16bits(u2[k] * scale);
        o1[4 + k] = bf16bits(u3[k] * scale);
    }
    if (q == 0) ndst[rb * 16 + c] = ss;              // 16 consecutive floats per wave
    *(bhalf8*)(dst + ((size_t)(rb * 2 + 0) * 64 + lane) * 8) = o0;
    *(bhalf8*)(dst + ((size_t)(rb * 2 + 1) * 64 + lane) * 8) = o1;
}

// ---------------- tile kernel: barrier-free, atomic-free K-loop; light-contention epilogue ----------------
// grid (mcp=4, nt=64, b=4) = 1024 blocks; wave tile 64 rows x 32 cols/step, 32 steps.
// Distance-2 register prefetch (4 named buffers, round-3/4 shape). Per-step col-min is
// q-reduced in-register (shfl_xor 16/32) so the block's 2048 col partials fit a 16 KB
// write-once colstore -> no mid-loop flush, no in-loop barrier, no in-loop atomics.
// Epilogue: plain disjoint rowpart stores; colpart atomicMin at 4-way contention only.
__global__ __launch_bounds__(256) void chamfer_tile(
        const unsigned short* __restrict__ Ap, const unsigned short* __restrict__ Bp,
        const float* __restrict__ nA, const float* __restrict__ nB,
        float* __restrict__ rowpart, int* __restrict__ colpart) {
    const int mcp = blockIdx.x;  // 0..3 : 2048-col chunk
    const int nt = blockIdx.y;   // 0..63
    const int b  = blockIdx.z;   // 0..3
    const int tid = threadIdx.x;
    const int wave = tid >> 6, lane = tid & 63;
    const int wr = wave >> 1, wc = wave & 1;
    const int q = lane >> 4, c = lane & 15;

    __shared__ float colstore[4096];  // 16 KB: [step 0..31][wave 0..3][c*2+jj], write-once
    __shared__ float nyb2[2048];      // 8 KB: all 2048 col norms (prologue-written)
    __shared__ int rowmin[128];

    // ---- prologue ----
    *(f32x4*)&nyb2[tid * 4] = *(const f32x4*)(nB + (size_t)b * 8192 + mcp * 2048 + tid * 4);
    *(f32x4*)&nyb2[1024 + tid * 4] =
        *(const f32x4*)(nB + (size_t)b * 8192 + mcp * 2048 + 1024 + tid * 4);
    if (tid < 128) rowmin[tid] = INF_BITS;

    const int rbA0 = b * 512 + nt * 8 + wr * 4;
    bhalf8 af[4][2];
    #pragma unroll
    for (int i = 0; i < 4; i++)
        #pragma unroll
        for (int ks = 0; ks < 2; ks++)
            af[i][ks] = *(const bhalf8*)(Ap + ((size_t)((rbA0 + i) * 2 + ks) * 64 + lane) * 8);

    f32x4 cnx[4];
    {
        const float* nrow = nA + (size_t)b * 8192 + nt * 128 + wr * 64 + q * 4;
        #pragma unroll
        for (int i = 0; i < 4; i++)
            cnx[i] = *(const f32x4*)(nrow + i * 16);
    }

    f32x4 rv[4];                 // running row-min, rows i*16+q*4+r
    #pragma unroll
    for (int i = 0; i < 4; i++) rv[i] = (f32x4){3.0e38f, 3.0e38f, 3.0e38f, 3.0e38f};

    __syncthreads();             // nyb2 + rowmin visible; the ONLY pre-epilogue barrier

    // step s (0..31): cols (s>>1)*128 + wc*64 + (s&1)*32 + jj*16 + c; rb stride 1024 shorts.
    const unsigned short* base = Bp + (size_t)(b * 512 + mcp * 128 + wc * 4) * 1024 + lane * 8;
    auto bptr = [&](int s) { return base + ((s >> 1) * 8192 + (s & 1) * 2048); };

    auto loadB = [&](const unsigned short* p, bhalf8 (&bf)[2][2]) {
        #pragma unroll
        for (int jj = 0; jj < 2; jj++)
            #pragma unroll
            for (int ks = 0; ks < 2; ks++)
                bf[jj][ks] = *(const bhalf8*)(p + jj * 1024 + ks * 512);
    };

    auto process = [&](int s, bhalf8 (&bf)[2][2]) {
        const int cb = (s >> 1) * 128 + wc * 64 + (s & 1) * 32 + c;
        const float ny0 = nyb2[cb];       // 4-way same-address broadcast, free
        const float ny1 = nyb2[cb + 16];

        f32x4 acc[4][2];
        #pragma unroll
        for (int i = 0; i < 4; i++)
            #pragma unroll
            for (int jj = 0; jj < 2; jj++)
                acc[i][jj] = __builtin_amdgcn_mfma_f32_16x16x32_bf16(af[i][0], bf[jj][0], cnx[i], 0, 0, 0);
        #pragma unroll
        for (int i = 0; i < 4; i++)
            #pragma unroll
            for (int jj = 0; jj < 2; jj++)
                acc[i][jj] = __builtin_amdgcn_mfma_f32_16x16x32_bf16(af[i][1], bf[jj][1], acc[i][jj], 0, 0, 0);

        // sv = full squared distance; row-min fused
        float sv[4][2][4];
        #pragma unroll
        for (int i = 0; i < 4; i++)
            #pragma unroll
            for (int r = 0; r < 4; r++) {
                sv[i][0][r] = acc[i][0][r] + ny0;
                sv[i][1][r] = acc[i][1][r] + ny1;
                rv[i][r] = min3f(sv[i][0][r], sv[i][1][r], rv[i][r]);
            }

        // col-min over this lane's 16 rows (min3 tree), then q-reduction (shfl_xor 16/32)
        float t[2];
        #pragma unroll
        for (int jj = 0; jj < 2; jj++) {
            float t0 = min3f(sv[0][jj][0], sv[0][jj][1], sv[0][jj][2]);
            float t1 = min3f(sv[0][jj][3], sv[1][jj][0], sv[1][jj][1]);
            float t2 = min3f(sv[1][jj][2], sv[1][jj][3], sv[2][jj][0]);
            float t3 = min3f(sv[2][jj][1], sv[2][jj][2], sv[2][jj][3]);
            float t4 = min3f(sv[3][jj][0], sv[3][jj][1], sv[3][jj][2]);
            float tt = fminf(min3f(t0, t1, t2), min3f(t3, t4, sv[3][jj][3]));
            tt = fminf(tt, __shfl_xor(tt, 16, 64));
            tt = fminf(tt, __shfl_xor(tt, 32, 64));   // full 64-row col-min in every lane
            t[jj] = tt;
        }
        if (lane < 16)   // 16 lanes x 8B contiguous -> conflict-free ds_write_b64
            *(float2*)&colstore[(s * 4 + wave) * 32 + c * 2] = make_float2(t[0], t[1]);
    };

    // ---- 4-buffer, distance-2 pipeline over 32 steps ----
    bhalf8 Bf0[2][2], Bf1[2][2], Bf2[2][2], Bf3[2][2];
    loadB(bptr(0), Bf0);
    loadB(bptr(1), Bf1);
    #pragma unroll 1
    for (int sp = 0; sp < 8; sp++) {     // steps 4sp .. 4sp+3
        const int s = sp * 4;
        loadB(bptr(s + 2), Bf2);  process(s,     Bf0);
        loadB(bptr(s + 3), Bf3);  process(s + 1, Bf1);
        loadB(bptr(s + 4), Bf0);  process(s + 2, Bf2);   // sp==7: over-read (in-workspace)
        loadB(bptr(s + 5), Bf1);  process(s + 3, Bf3);   // sp==7: over-read (in-workspace)
    }

    // ---- epilogue: LDS row-min combine; plain rowpart stores; 4-way-contention colpart ----
    #pragma unroll
    for (int i = 0; i < 4; i++)
        #pragma unroll
        for (int r = 0; r < 4; r++)
            atomicMin(&rowmin[wr * 64 + i * 16 + q * 4 + r], __float_as_int(rv[i][r]));
    __syncthreads();                     // rowmin + all colstore writes visible

    if (tid < 128)
        rowpart[(size_t)mcp * 32768 + ((size_t)b * 64 + nt) * 128 + tid] =
            __int_as_float(rowmin[tid]);

    // colpart slot = nt & 15: 4 contributor blocks per address (vs 64-70 in round 4),
    // fire-and-forget atomicMin (no return), coalesced 2048 consecutive ints per block.
    int* cp = colpart + ((size_t)(b * 16 + (nt & 15))) * 8192 + mcp * 2048;
    #pragma unroll
    for (int k = 0; k < 8; k++) {
        const int col = k * 256 + tid;   // 0..2047
        const int s  = (col >> 7) * 2 + ((col >> 5) & 1);
        const int wcx = (col >> 6) & 1, jf = (col >> 4) & 1, cx = col & 15;
        const float m = fminf(colstore[(s * 4 + wcx)     * 32 + cx * 2 + jf],    // wr=0 wave
                              colstore[(s * 4 + 2 + wcx) * 32 + cx * 2 + jf]);   // wr=1 wave
        atomicMin(&cp[col], __float_as_int(m));
    }
}

// ---------------- finalize: min-reduce partials (2.5 MB) -> scalar ----------------
__global__ __launch_bounds__(256) void chamfer_finalize(
        const float* __restrict__ rowpart, const int* __restrict__ colpart,
        float* __restrict__ out) {
    const int gid = blockIdx.x * 256 + threadIdx.x;   // 64 blocks -> 16384 threads
    float s = 0.f;
    #pragma unroll
    for (int k = 0; k < 2; k++) {
        const int p = gid + k * 16384;                // 0..32767
        // rows: min over 4 mcp partials
        float rm = fminf(fminf(rowpart[p], rowpart[32768 + p]),
                         fminf(rowpart[65536 + p], rowpart[98304 + p]));
        // cols: min over 16 slots (consecutive gid -> consecutive col: coalesced)
        const int bb = p >> 13, col = p & 8191;
        const int* cbase = colpart + (size_t)bb * 16 * 8192 + col;
        float cm = 3.0e38f;
        #pragma unroll
        for (int sl = 0; sl < 16; sl++)
            cm = fminf(cm, __int_as_float(cbase[(size_t)sl * 8192]));
        s += rm * (1.0f / 32768.f) + cm * (1.0f / 32768.f);   // 1/(B*N) == 1/(B*M)
    }
    __shared__ float sb[256];
    const int tid = threadIdx.x;
    sb[tid] = s;
    __syncthreads();
    for (int st = 128; st > 0; st >>= 1) {
        if (tid < st) sb[tid] += sb[tid + st];
        __syncthreads();
    }
    if (tid == 0) atomicAdd(out, sb[0]);
}

extern "C" void kernel_launch(void* const* d_in, const int* in_sizes, int n_in,
                              void* d_out, int out_size, void* d_ws, size_t ws_size,
                              hipStream_t stream) {
    const float* f  = (const float*)d_in[0];
    const float* f2 = (const float*)d_in[1];
    char* ws = (char*)d_ws;
    unsigned short* Ap = (unsigned short*)(ws + OFF_A);
    unsigned short* Bp = (unsigned short*)(ws + OFF_B);
    float* nA      = (float*)(ws + OFF_NA);
    float* nB      = (float*)(ws + OFF_NB);
    float* rowpart = (float*)(ws + OFF_RP);
    int*   colpart = (int*)(ws + OFF_CP);
    float* out     = (float*)d_out;

    // prep: K=64 fragment layout + fp32 norms; inits colpart/out
    chamfer_prep<<<dim3(1024), dim3(256), 0, stream>>>(f, f2, Ap, Bp, nA, nB, colpart, out);

    // main: 1024 blocks, 32-step barrier-free atomic-free loop, distance-2 prefetch
    chamfer_tile<<<dim3(4, NT_, B_), dim3(256), 0, stream>>>(Ap, Bp, nA, nB, rowpart, colpart);

    // finalize: 2.5 MB partial-min reduce -> scalar
    chamfer_finalize<<<dim3(64), dim3(256), 0, stream>>>(rowpart, colpart, out);
}